// Round 4
// baseline (143.489 us; speedup 1.0000x reference)
//
#include <hip/hip_runtime.h>

// ConvCaps (Matrix Capsules w/ EM routing), MI355X fp32.
// One block per output position: 784 blocks x 512 threads (8 waves).
// Thread map: c = wv*4 + (lane&3)  (class, 0..31)
//             sub = lane>>2        (n-slice, 0..15), each owns 9 n's.
// r in registers; votes recomputed per pass (LDS poses + L2-resident W).
// Cross-sub reduction: masks {4,16,32} via shfl, mask 8 via DPP row_ror:8
// (stays in the VALU pipe, no LDS permute). S0 never reduced: sum(coeff)
// == rs/(rs+eps) analytically. All divides -> v_rcp_f32.

namespace {

constexpr int OHW  = 14;
constexpr int NPOS = 4 * OHW * OHW;     // 784
constexpr int NN   = 144;               // 3*3*16
constexpr int CC   = 32;
constexpr int KPER = 9;                 // n's per thread
constexpr float LAMB  = 0.01f;
constexpr float EPSF  = 1e-6f;
constexpr float LN2PI = 1.8378770664093453f;
constexpr int PSTR = 20;                // sP row stride (dwords)
constexpr int RS   = 33;                // ln_ap / r row stride (conflict-free)

__device__ __forceinline__ float rcpf(float x) { return __builtin_amdgcn_rcpf(x); }

// lane ^ 8 exchange via DPP row_ror:8 (rows of 16: (i+8)%16 == i^8)
__device__ __forceinline__ float xor8_dpp(float x) {
  int y = __builtin_amdgcn_update_dpp(0, __float_as_int(x), 0x128, 0xF, 0xF, true);
  return __int_as_float(y);
}

__device__ __forceinline__ float reduce_sub16(float x) {
  x += __shfl_xor(x, 4);
  x += xor8_dpp(x);
  x += __shfl_xor(x, 16);
  x += __shfl_xor(x, 32);
  return x;
}

__global__ __launch_bounds__(512, 2)
void convcaps_em(const float* __restrict__ x,
                 const float* __restrict__ a,
                 const float* __restrict__ w,        // (144, 32, 4, 4)
                 const float* __restrict__ beta_u,
                 const float* __restrict__ beta_a,
                 const int*   __restrict__ iters_p,
                 float* __restrict__ out_mu,         // (4,14,14,32,16)
                 float* __restrict__ out_a)          // (4,14,14,32,1)
{
  __shared__ __align__(16) float sP[NN * PSTR];
  __shared__ float sA[NN];
  __shared__ float sL[NN * RS];                      // ln_ap / r exchange

  const int tid = threadIdx.x;
  const int pos = blockIdx.x;
  const int b   = pos / (OHW * OHW);
  const int rem = pos - b * (OHW * OHW);
  const int oi  = rem / OHW;
  const int oj  = rem - oi * OHW;

  int iters = iters_p[0];
  iters = (iters < 1) ? 1 : (iters > 16 ? 16 : iters);

  // ---- stage pose patch (576 float4) + activations ----
  {
    {
      const int n = tid >> 2, j = tid & 3;
      const int kh = n / 48, kw = (n >> 4) % 3, bc = n & 15;
      const float4 val = *(const float4*)(x + ((((b * 16 + oi + kh) * 16) + (oj + kw)) * 256 + bc * 16 + j * 4));
      *(float4*)(sP + n * PSTR + j * 4) = val;
    }
    if (tid < 64) {
      const int g = 512 + tid;
      const int n = g >> 2, j = g & 3;
      const int kh = n / 48, kw = (n >> 4) % 3, bc = n & 15;
      const float4 val = *(const float4*)(x + ((((b * 16 + oi + kh) * 16) + (oj + kw)) * 256 + bc * 16 + j * 4));
      *(float4*)(sP + n * PSTR + j * 4) = val;
    }
    if (tid < NN) {
      const int kh = tid / 48, kw = (tid >> 4) % 3, bc = tid & 15;
      sA[tid] = a[(((b * 16 + oi + kh) * 16) + (oj + kw)) * 16 + bc];
    }
  }
  __syncthreads();

  const int lane = tid & 63;
  const int wv   = tid >> 6;                 // 0..7
  const int c    = wv * 4 + (lane & 3);      // 0..31
  const int sub  = lane >> 2;                // 0..15
  const int n0   = sub * KPER;
  const float bu = beta_u[c];
  const float ba = beta_a[c];
  const float* __restrict__ wc = w + c * 16; // + n*512

  float r[KPER];
  #pragma unroll
  for (int k = 0; k < KPER; ++k) r[k] = sA[n0 + k] * (1.0f / CC);

  float mu[16], hi[16];   // in E-pass reused as B[], A[]

  for (int it = 0; it < iters; ++it) {
    // ---- r_sum over n for class c ----
    float rs = 0.f;
    #pragma unroll
    for (int k = 0; k < KPER; ++k) rs += r[k];
    rs = reduce_sub16(rs);
    const float inv = rcpf(rs + EPSF);
    const float S0t = rs * inv;              // == sum(coeff), exact

    // ---- M-step: S1/S2 over this thread's 9 n's (votes recomputed) ----
    float S1[16], S2[16];
    #pragma unroll
    for (int p = 0; p < 16; ++p) { S1[p] = 0.f; S2[p] = 0.f; }

    #pragma unroll 3
    for (int k = 0; k < KPER; ++k) {
      const int n = n0 + k;
      const float4* Wp = (const float4*)(wc + n * 512);
      const float4 w0 = Wp[0], w1 = Wp[1], w2 = Wp[2], w3 = Wp[3];
      const float coeff = r[k] * inv;
      #pragma unroll
      for (int i = 0; i < 4; ++i) {
        const float4 pr = *(const float4*)(sP + n * PSTR + i * 4);
        const float v0 = fmaf(pr.x, w0.x, fmaf(pr.y, w1.x, fmaf(pr.z, w2.x, pr.w * w3.x)));
        const float v1 = fmaf(pr.x, w0.y, fmaf(pr.y, w1.y, fmaf(pr.z, w2.y, pr.w * w3.y)));
        const float v2 = fmaf(pr.x, w0.z, fmaf(pr.y, w1.z, fmaf(pr.z, w2.z, pr.w * w3.z)));
        const float v3 = fmaf(pr.x, w0.w, fmaf(pr.y, w1.w, fmaf(pr.z, w2.w, pr.w * w3.w)));
        S1[4*i+0] = fmaf(coeff, v0, S1[4*i+0]);  S2[4*i+0] = fmaf(coeff * v0, v0, S2[4*i+0]);
        S1[4*i+1] = fmaf(coeff, v1, S1[4*i+1]);  S2[4*i+1] = fmaf(coeff * v1, v1, S2[4*i+1]);
        S1[4*i+2] = fmaf(coeff, v2, S1[4*i+2]);  S2[4*i+2] = fmaf(coeff * v2, v2, S2[4*i+2]);
        S1[4*i+3] = fmaf(coeff, v3, S1[4*i+3]);  S2[4*i+3] = fmaf(coeff * v3, v3, S2[4*i+3]);
      }
    }

    // ---- reduce across 16 sub-lanes (all lanes keep full sums) ----
    #pragma unroll
    for (int p = 0; p < 16; ++p) { S1[p] += __shfl_xor(S1[p], 4);  S2[p] += __shfl_xor(S2[p], 4);  }
    #pragma unroll
    for (int p = 0; p < 16; ++p) { S1[p] += xor8_dpp(S1[p]);       S2[p] += xor8_dpp(S2[p]);       }
    #pragma unroll
    for (int p = 0; p < 16; ++p) { S1[p] += __shfl_xor(S1[p], 16); S2[p] += __shfl_xor(S2[p], 16); }
    #pragma unroll
    for (int p = 0; p < 16; ++p) { S1[p] += __shfl_xor(S1[p], 32); S2[p] += __shfl_xor(S2[p], 32); }

    // ---- per-class stats (redundant across sub-lanes) ----
    const float g2 = 2.0f - S0t;
    float logsum = 0.f;
    #pragma unroll
    for (int p = 0; p < 16; ++p) {
      const float m = S1[p];
      float sig = S2[p] - m * m * g2 + EPSF;   // sum coeff*(v-mu)^2 + eps
      sig = fmaxf(sig, 1e-12f);
      logsum += __logf(sig);
      mu[p] = m;
      hi[p] = 0.5f * rcpf(sig);
    }
    const float cost = rs * (16.0f * bu + 0.5f * logsum);
    const float aout = rcpf(1.0f + __expf(-LAMB * (ba - cost)));

    if (it == iters - 1) {
      if (sub == 0) {
        float4* om = (float4*)(out_mu + (size_t)pos * 512 + c * 16);
        om[0] = make_float4(mu[0],  mu[1],  mu[2],  mu[3]);
        om[1] = make_float4(mu[4],  mu[5],  mu[6],  mu[7]);
        om[2] = make_float4(mu[8],  mu[9],  mu[10], mu[11]);
        om[3] = make_float4(mu[12], mu[13], mu[14], mu[15]);
        out_a[pos * CC + c] = aout;
      }
    } else {
      // ---- E-step: ln_ap = kc' - sum_p v*(A*v + B), A=hi, B=-2*hi*mu ----
      float D = 0.f;
      #pragma unroll
      for (int p = 0; p < 16; ++p) {
        const float m = mu[p];
        D = fmaf(hi[p] * m, m, D);
        mu[p] = -2.0f * hi[p] * m;             // B[p]
      }
      const float kc = __logf(aout + EPSF) - 0.5f * logsum - 8.0f * LN2PI - D;
      #pragma unroll 3
      for (int k = 0; k < KPER; ++k) {
        const int n = n0 + k;
        const float4* Wp = (const float4*)(wc + n * 512);
        const float4 w0 = Wp[0], w1 = Wp[1], w2 = Wp[2], w3 = Wp[3];
        float s = 0.f;
        #pragma unroll
        for (int i = 0; i < 4; ++i) {
          const float4 pr = *(const float4*)(sP + n * PSTR + i * 4);
          const float v0 = fmaf(pr.x, w0.x, fmaf(pr.y, w1.x, fmaf(pr.z, w2.x, pr.w * w3.x)));
          const float v1 = fmaf(pr.x, w0.y, fmaf(pr.y, w1.y, fmaf(pr.z, w2.y, pr.w * w3.y)));
          const float v2 = fmaf(pr.x, w0.z, fmaf(pr.y, w1.z, fmaf(pr.z, w2.z, pr.w * w3.z)));
          const float v3 = fmaf(pr.x, w0.w, fmaf(pr.y, w1.w, fmaf(pr.z, w2.w, pr.w * w3.w)));
          s = fmaf(fmaf(hi[4*i+0], v0, mu[4*i+0]), v0, s);
          s = fmaf(fmaf(hi[4*i+1], v1, mu[4*i+1]), v1, s);
          s = fmaf(fmaf(hi[4*i+2], v2, mu[4*i+2]), v2, s);
          s = fmaf(fmaf(hi[4*i+3], v3, mu[4*i+3]), v3, s);
        }
        sL[n * RS + c] = kc - s;
      }
      __syncthreads();
      // ---- softmax over classes per n (2 threads per capsule) ----
      if (tid < 2 * NN) {
        const int n = tid >> 1, hf = (tid & 1) << 4;
        float xv[16];
        float mx = -3.0e38f;
        #pragma unroll
        for (int q = 0; q < 16; ++q) { xv[q] = sL[n * RS + hf + q]; mx = fmaxf(mx, xv[q]); }
        mx = fmaxf(mx, __shfl_xor(mx, 1));
        float ssum = 0.f;
        #pragma unroll
        for (int q = 0; q < 16; ++q) { xv[q] = __expf(xv[q] - mx); ssum += xv[q]; }
        ssum += __shfl_xor(ssum, 1);
        const float sc = sA[n] * rcpf(ssum);
        #pragma unroll
        for (int q = 0; q < 16; ++q) sL[n * RS + hf + q] = xv[q] * sc;
      }
      __syncthreads();
      // ---- read back this thread's r ----
      #pragma unroll
      for (int k = 0; k < KPER; ++k) r[k] = sL[(n0 + k) * RS + c];
    }
  }
}

} // namespace

extern "C" void kernel_launch(void* const* d_in, const int* in_sizes, int n_in,
                              void* d_out, int out_size, void* d_ws, size_t ws_size,
                              hipStream_t stream) {
  const float* x  = (const float*)d_in[0];
  const float* a  = (const float*)d_in[1];
  const float* w  = (const float*)d_in[2];
  const float* bu = (const float*)d_in[3];
  const float* ba = (const float*)d_in[4];
  const int* iters = (const int*)d_in[5];

  float* out_mu = (float*)d_out;                       // 401408
  float* out_a  = out_mu + (size_t)NPOS * CC * 16;     // 25088

  convcaps_em<<<NPOS, 512, 0, stream>>>(x, a, w, bu, ba, iters, out_mu, out_a);
}